// Round 9
// baseline (299.156 us; speedup 1.0000x reference)
//
#include <hip/hip_runtime.h>
#include <hip/hip_bf16.h>

#define N_NODES 100000
#define D 256
#define R_REL 8
#define E_EDGES 40000
#define LN_EPS 1e-5f
#define ETOT (R_REL * E_EDGES)                    // 320000
#define SCAN_CH 1024
#define SCAN_NB ((N_NODES + SCAN_CH - 1) / SCAN_CH)  // 98
#define NROWT ((N_NODES + 127) / 128)             // 782
#define NWG (NROWT * 10)                          // 7820

typedef __attribute__((ext_vector_type(8))) short short8;
typedef __attribute__((ext_vector_type(4))) float f32x4;
typedef unsigned char uchar;

__device__ inline ushort bf16u(float f) {
    __hip_bfloat16 h = __float2bfloat16(f);
    return *reinterpret_cast<ushort*>(&h);
}
__device__ inline float bf2f(ushort u) { return __uint_as_float(((unsigned)u) << 16); }

// ---------------------------------------------------------------------------
// BT[o][d] = BigB[d][o] bf16, BigB = [w_self | bases0..3] (256 x 1280).
__global__ __launch_bounds__(256) void k_prepB(const float* __restrict__ w_self,
                                               const float* __restrict__ bases,
                                               ushort* __restrict__ BT) {
    __shared__ float tile[64][65];
    int ot = blockIdx.x >> 2, dt = blockIdx.x & 3;
    int o0 = ot * 64, d0 = dt * 64;
    int m = o0 >> 8;                       // 0 = w_self, 1..4 = bases[m-1]
    const float* src = (m == 0) ? w_self : bases + (size_t)(m - 1) * D * D;
    int ol0 = o0 & 255;
    int t = threadIdx.x;
    int cl = t & 63, rw = t >> 6;
    for (int i = 0; i < 16; ++i) {
        int dl = i * 4 + rw;
        tile[dl][cl] = src[(size_t)(d0 + dl) * D + ol0 + cl];
    }
    __syncthreads();
    for (int i = 0; i < 16; ++i) {
        int ol = i * 4 + rw;
        BT[(size_t)(o0 + ol) * D + d0 + cl] = bf16u(tile[cl][ol]);
    }
}

// ---------------------------------------------------------------------------
// CSR over dst (all relations together)
__global__ void k_count(const int* __restrict__ ei, int* __restrict__ cnt) {
    int idx = blockIdx.x * blockDim.x + threadIdx.x;
    if (idx >= ETOT) return;
    int r = idx / E_EDGES, e = idx % E_EDGES;
    int dst = ei[(r * 2 + 1) * E_EDGES + e];
    atomicAdd(&cnt[dst], 1);
}

__global__ __launch_bounds__(256) void k_scanA(const int* __restrict__ cnt,
                                               int* __restrict__ start,
                                               int* __restrict__ sumsA) {
    __shared__ int sc[256];
    int t = threadIdx.x;
    int base = blockIdx.x * SCAN_CH + t * 4;
    int v0 = (base + 0 < N_NODES) ? cnt[base + 0] : 0;
    int v1 = (base + 1 < N_NODES) ? cnt[base + 1] : 0;
    int v2 = (base + 2 < N_NODES) ? cnt[base + 2] : 0;
    int v3 = (base + 3 < N_NODES) ? cnt[base + 3] : 0;
    int ts = v0 + v1 + v2 + v3;
    sc[t] = ts;
    __syncthreads();
    for (int off = 1; off < 256; off <<= 1) {
        int val = (t >= off) ? sc[t - off] : 0;
        __syncthreads();
        sc[t] += val;
        __syncthreads();
    }
    int excl = sc[t] - ts;
    if (base + 0 < N_NODES) start[base + 0] = excl;
    if (base + 1 < N_NODES) start[base + 1] = excl + v0;
    if (base + 2 < N_NODES) start[base + 2] = excl + v0 + v1;
    if (base + 3 < N_NODES) start[base + 3] = excl + v0 + v1 + v2;
    if (t == 255) sumsA[blockIdx.x] = sc[255];
}

__global__ __launch_bounds__(256) void k_scanB(const int* __restrict__ sumsA,
                                               int* __restrict__ sumsB) {
    __shared__ int sc[256];
    int t = threadIdx.x;
    int i0 = t * 4;
    int v0 = (i0 + 0 < SCAN_NB) ? sumsA[i0 + 0] : 0;
    int v1 = (i0 + 1 < SCAN_NB) ? sumsA[i0 + 1] : 0;
    int v2 = (i0 + 2 < SCAN_NB) ? sumsA[i0 + 2] : 0;
    int v3 = (i0 + 3 < SCAN_NB) ? sumsA[i0 + 3] : 0;
    int ts = v0 + v1 + v2 + v3;
    sc[t] = ts;
    __syncthreads();
    for (int off = 1; off < 256; off <<= 1) {
        int val = (t >= off) ? sc[t - off] : 0;
        __syncthreads();
        sc[t] += val;
        __syncthreads();
    }
    int excl = sc[t] - ts;
    if (i0 + 0 < SCAN_NB) sumsB[i0 + 0] = excl;
    if (i0 + 1 < SCAN_NB) sumsB[i0 + 1] = excl + v0;
    if (i0 + 2 < SCAN_NB) sumsB[i0 + 2] = excl + v0 + v1;
    if (i0 + 3 < SCAN_NB) sumsB[i0 + 3] = excl + v0 + v1 + v2;
}

__global__ __launch_bounds__(256) void k_scanC(int* __restrict__ start,
                                               const int* __restrict__ sumsB,
                                               int* __restrict__ cursor) {
    int idx = blockIdx.x * blockDim.x + threadIdx.x;
    if (idx < N_NODES) {
        int v = start[idx] + sumsB[idx / SCAN_CH];
        start[idx] = v;
        cursor[idx] = v;
    }
    if (idx == 0) start[N_NODES] = ETOT;
}

// payload = (r<<20) | src, slotted per dst
__global__ void k_scatter(const int* __restrict__ ei, int* __restrict__ cursor,
                          int* __restrict__ payload) {
    int idx = blockIdx.x * blockDim.x + threadIdx.x;
    if (idx >= ETOT) return;
    int r = idx / E_EDGES, e = idx % E_EDGES;
    int src = ei[r * 2 * E_EDGES + e];
    int dst = ei[(r * 2 + 1) * E_EDGES + e];
    int pos = atomicAdd(&cursor[dst], 1);
    payload[pos] = (r << 20) | src;
}

// ---------------------------------------------------------------------------
// [hb | U] = bf16(x) @ BT^T.  128x128 tile, BK=64.
// Flattened grid + m204 bijective XCD swizzle: all 10 passes of a row-tile
// run on one XCD -> A-tile and BT are per-XCD L2-resident; x HBM-fetched once.
// A: reg-staged f32->bf16 (T14 split: load early, cvt+ds_write after MFMA).
// B: global_load_lds, linear dest, inverse-swizzled source (T21).
// pass 0..1 -> hb (bf16); pass 2..9 -> U plane (fp8 e4m3, value*64).
__global__ __launch_bounds__(256, 2) void k_gemm(const float* __restrict__ x,
                                                 const ushort* __restrict__ BT,
                                                 ushort* __restrict__ hb,
                                                 uchar* __restrict__ U) {
    __shared__ ushort As[2][128 * 64];     // 2 x 16 KB
    __shared__ ushort Bs[2][128 * 64];     // 2 x 16 KB
    int t = threadIdx.x;

    // m204 bijective XCD-chunked swizzle (NWG = 7820, 8 XCDs)
    const int q = NWG / 8, r8 = NWG % 8;
    int dd = blockIdx.x;
    int xcd = dd & 7, slot = dd >> 3;
    int wgid = (xcd < r8 ? xcd * (q + 1) : r8 * (q + 1) + (xcd - r8) * q) + slot;
    int rowtile = wgid / 10, pass = wgid % 10;
    int row0 = rowtile * 128;

    int l = t & 63, w = t >> 6;
    int wr = w >> 1, wc = w & 1;           // 2 x 2 wave grid
    int lr = l & 15, lg = l >> 4;

    auto stageB = [&](int buf, int kt) {
#pragma unroll
        for (int p = 0; p < 4; ++p) {
            int o = p * 4096 + t * 16;
            int rowB = o >> 7;
            int colb = (o & 127) ^ ((rowB & 7) << 4);
            const char* gp = (const char*)BT +
                ((size_t)(pass * 128 + rowB) * D + kt * 64) * 2 + colb;
            char* lp = (char*)&Bs[buf][0] + p * 4096 + (t >> 6) * 1024;
            __builtin_amdgcn_global_load_lds(
                (const __attribute__((address_space(1))) void*)gp,
                (__attribute__((address_space(3))) void*)lp, 16, 0, 0);
        }
    };
    // A: load 8 float4 (two per 16B-dest chunk) into regs
    auto loadA = [&](float4 fa[8], int kt) {
#pragma unroll
        for (int p = 0; p < 4; ++p) {
            int cid = p * 256 + t;         // chunk 0..1023 (16B each)
            int rowA = cid >> 3;
            int kc = cid & 7;
            int srcrow = min(row0 + rowA, N_NODES - 1);
            const float4* xp = (const float4*)(x + (size_t)srcrow * D + kt * 64 + kc * 8);
            fa[p * 2] = xp[0]; fa[p * 2 + 1] = xp[1];
        }
    };
    auto writeA = [&](int buf, const float4 fa[8]) {
#pragma unroll
        for (int p = 0; p < 4; ++p) {
            int cid = p * 256 + t;
            int rowA = cid >> 3;
            int kc = cid & 7;
            float4 f0 = fa[p * 2], f1 = fa[p * 2 + 1];
            short8 v;
            v[0] = (short)bf16u(f0.x); v[1] = (short)bf16u(f0.y);
            v[2] = (short)bf16u(f0.z); v[3] = (short)bf16u(f0.w);
            v[4] = (short)bf16u(f1.x); v[5] = (short)bf16u(f1.y);
            v[6] = (short)bf16u(f1.z); v[7] = (short)bf16u(f1.w);
            int bo = rowA * 128 + ((kc * 16) ^ ((rowA & 7) << 4));
            *(short8*)((char*)&As[buf][0] + bo) = v;
        }
    };

    f32x4 acc[4][4] = {};
    // prologue: fill buf 0
    stageB(0, 0);
    {
        float4 fa[8];
        loadA(fa, 0);
        writeA(0, fa);
    }
    int buf = 0;
    for (int kt = 0; kt < 4; ++kt) {
        __syncthreads();                   // buf ready
        float4 fa[8];
        if (kt < 3) { stageB(buf ^ 1, kt + 1); loadA(fa, kt + 1); }
#pragma unroll
        for (int kk = 0; kk < 2; ++kk) {
            int kb = kk * 64 + lg * 16;
            short8 a[4], b[4];
#pragma unroll
            for (int mi = 0; mi < 4; ++mi) {
                int row = wr * 64 + mi * 16 + lr;
                a[mi] = *(const short8*)((const char*)&As[buf][0] +
                         row * 128 + (kb ^ ((row & 7) << 4)));
            }
#pragma unroll
            for (int ni = 0; ni < 4; ++ni) {
                int rb = wc * 64 + ni * 16 + lr;
                b[ni] = *(const short8*)((const char*)&Bs[buf][0] +
                         rb * 128 + (kb ^ ((rb & 7) << 4)));
            }
#pragma unroll
            for (int mi = 0; mi < 4; ++mi)
#pragma unroll
                for (int ni = 0; ni < 4; ++ni)
                    acc[mi][ni] = __builtin_amdgcn_mfma_f32_16x16x32_bf16(
                        a[mi], b[ni], acc[mi][ni], 0, 0, 0);
        }
        if (kt < 3) writeA(buf ^ 1, fa);
        buf ^= 1;
    }

    // ---- epilogue (regs only)
    if (pass < 2) {
        int colbase = pass * 128 + wc * 64 + lr;
#pragma unroll
        for (int mi = 0; mi < 4; ++mi)
#pragma unroll
            for (int j = 0; j < 4; ++j) {
                int row = row0 + wr * 64 + mi * 16 + lg * 4 + j;
                if (row < N_NODES) {
                    ushort* op = hb + (size_t)row * D + colbase;
#pragma unroll
                    for (int ni = 0; ni < 4; ++ni) op[ni * 16] = bf16u(acc[mi][ni][j]);
                }
            }
    } else {
        int pl = pass - 2;
        int plane = pl >> 1;
        int colbase = (pl & 1) * 128 + wc * 64 + lr;
#pragma unroll
        for (int mi = 0; mi < 4; ++mi)
#pragma unroll
            for (int j = 0; j < 4; ++j) {
                int row = row0 + wr * 64 + mi * 16 + lg * 4 + j;
                if (row < N_NODES) {
                    // U layout: [src][plane*256 + col], fp8 e4m3 of value*64
                    uchar* up = U + (size_t)row * 1024 + plane * 256 + colbase;
                    unsigned p01 = __builtin_amdgcn_cvt_pk_fp8_f32(
                        acc[mi][0][j] * 64.0f, acc[mi][1][j] * 64.0f, 0, 0);
                    unsigned p23 = __builtin_amdgcn_cvt_pk_fp8_f32(
                        acc[mi][2][j] * 64.0f, acc[mi][3][j] * 64.0f, 0, 0);
                    up[0]  = (uchar)(p01 & 0xFF);
                    up[16] = (uchar)((p01 >> 8) & 0xFF);
                    up[32] = (uchar)(p23 & 0xFF);
                    up[48] = (uchar)((p23 >> 8) & 0xFF);
                }
            }
    }
}

// ---------------------------------------------------------------------------
// Per dst node (one wave each). Lane owns output cols lane*4..lane*4+3.
// Per edge: one dword per plane (4 coalesced 256B wave-loads), coeff row as
// ds_read_b128, accumulate in regs. NO cross-lane work until the LN reduce.
__global__ __launch_bounds__(256) void k_final(float* __restrict__ out,
                                               const ushort* __restrict__ hb,
                                               const uchar* __restrict__ U,
                                               const int* __restrict__ start,
                                               const int* __restrict__ payload,
                                               const float* __restrict__ coeff,
                                               const float* __restrict__ bias,
                                               const float* __restrict__ gamma,
                                               const float* __restrict__ beta) {
    __shared__ float cf[32];
    int t = threadIdx.x;
    if (t < 32) cf[t] = coeff[t];
    __syncthreads();
    int lane = t & 63, w = t >> 6;
    int n = blockIdx.x * 4 + w;
    int s = start[n], e = start[n + 1];

    // per-relation degree counts packed 8x8 bits
    unsigned long long cnt64 = 0;
    for (int p = s; p < e; ++p)
        cnt64 += 1ull << ((payload[p] >> 20) * 8);

    float msg[4] = {0.f, 0.f, 0.f, 0.f};
    for (int p = s; p < e; ++p) {
        int pk = payload[p];
        int r = pk >> 20, src = pk & 0xFFFFF;
        float dg = (float)((unsigned)(cnt64 >> (r * 8)) & 255u);
        float inv = __builtin_amdgcn_rcpf(dg) * 0.015625f;
        float4 wv = *(const float4*)&cf[r * 4];
        const uchar* up = U + (size_t)src * 1024 + lane * 4;
        unsigned v0 = *(const unsigned*)(up);
        unsigned v1 = *(const unsigned*)(up + 256);
        unsigned v2 = *(const unsigned*)(up + 512);
        unsigned v3 = *(const unsigned*)(up + 768);
        float w0 = wv.x * inv, w1 = wv.y * inv, w2 = wv.z * inv, w3 = wv.w * inv;
        msg[0] += w0 * __builtin_amdgcn_cvt_f32_fp8(v0, 0)
                + w1 * __builtin_amdgcn_cvt_f32_fp8(v1, 0)
                + w2 * __builtin_amdgcn_cvt_f32_fp8(v2, 0)
                + w3 * __builtin_amdgcn_cvt_f32_fp8(v3, 0);
        msg[1] += w0 * __builtin_amdgcn_cvt_f32_fp8(v0, 1)
                + w1 * __builtin_amdgcn_cvt_f32_fp8(v1, 1)
                + w2 * __builtin_amdgcn_cvt_f32_fp8(v2, 1)
                + w3 * __builtin_amdgcn_cvt_f32_fp8(v3, 1);
        msg[2] += w0 * __builtin_amdgcn_cvt_f32_fp8(v0, 2)
                + w1 * __builtin_amdgcn_cvt_f32_fp8(v1, 2)
                + w2 * __builtin_amdgcn_cvt_f32_fp8(v2, 2)
                + w3 * __builtin_amdgcn_cvt_f32_fp8(v3, 2);
        msg[3] += w0 * __builtin_amdgcn_cvt_f32_fp8(v0, 3)
                + w1 * __builtin_amdgcn_cvt_f32_fp8(v1, 3)
                + w2 * __builtin_amdgcn_cvt_f32_fp8(v2, 3)
                + w3 * __builtin_amdgcn_cvt_f32_fp8(v3, 3);
    }

    int col = lane * 4;
    size_t ro = (size_t)n * D + col;
    ushort4 hu = *(const ushort4*)&hb[ro];
    float4 bv = *(const float4*)&bias[col];
    float a[4];
    a[0] = bf2f(hu.x) + bv.x + msg[0];
    a[1] = bf2f(hu.y) + bv.y + msg[1];
    a[2] = bf2f(hu.z) + bv.z + msg[2];
    a[3] = bf2f(hu.w) + bv.w + msg[3];
    float sum = 0.f, sq = 0.f;
#pragma unroll
    for (int j = 0; j < 4; ++j) {
        a[j] = a[j] / (1.f + expf(-a[j]));
        sum += a[j]; sq += a[j] * a[j];
    }
#pragma unroll
    for (int off = 32; off >= 1; off >>= 1) {
        sum += __shfl_xor(sum, off, 64);
        sq  += __shfl_xor(sq,  off, 64);
    }
    float mean = sum * (1.0f / 256.0f);
    float var = sq * (1.0f / 256.0f) - mean * mean;
    float rs = rsqrtf(var + LN_EPS);
    float4 g4 = *(const float4*)&gamma[col];
    float4 b4 = *(const float4*)&beta[col];
    float4 o4;
    o4.x = (a[0] - mean) * rs * g4.x + b4.x;
    o4.y = (a[1] - mean) * rs * g4.y + b4.y;
    o4.z = (a[2] - mean) * rs * g4.z + b4.z;
    o4.w = (a[3] - mean) * rs * g4.w + b4.w;
    *(float4*)&out[ro] = o4;
}

// ---------------------------------------------------------------------------
extern "C" void kernel_launch(void* const* d_in, const int* in_sizes, int n_in,
                              void* d_out, int out_size, void* d_ws, size_t ws_size,
                              hipStream_t stream) {
    const float* x      = (const float*)d_in[0];
    const int*   ei     = (const int*)d_in[1];
    const float* bases  = (const float*)d_in[2];
    const float* coeff  = (const float*)d_in[3];
    const float* w_self = (const float*)d_in[4];
    const float* b_self = (const float*)d_in[5];
    const float* gamma  = (const float*)d_in[6];
    const float* beta   = (const float*)d_in[7];
    float* out = (float*)d_out;

    ushort* BT  = (ushort*)d_ws;                          // 1280*256 bf16 (0.66 MB)
    ushort* hb  = BT + (size_t)1280 * D;                  // N*256 bf16 (51.2 MB)
    uchar*  U   = (uchar*)(hb + (size_t)N_NODES * D);     // N*1024 fp8 (102.4 MB)
    int* cnt    = (int*)(U + (size_t)N_NODES * 1024);     // N
    int* start  = cnt + N_NODES;                          // N+1
    int* cursor = start + N_NODES + 1;                    // N
    int* sumsA  = cursor + N_NODES;                       // 98 (pad 128)
    int* sumsB  = sumsA + 128;                            // 98 (pad 128)
    int* payload = sumsB + 128;                           // ETOT

    hipMemsetAsync(cnt, 0, (size_t)N_NODES * sizeof(int), stream);

    k_prepB<<<80, 256, 0, stream>>>(w_self, bases, BT);
    k_count<<<(ETOT + 255) / 256, 256, 0, stream>>>(ei, cnt);
    k_scanA<<<SCAN_NB, 256, 0, stream>>>(cnt, start, sumsA);
    k_scanB<<<1, 256, 0, stream>>>(sumsA, sumsB);
    k_scanC<<<(N_NODES + 255) / 256, 256, 0, stream>>>(start, sumsB, cursor);
    k_scatter<<<(ETOT + 255) / 256, 256, 0, stream>>>(ei, cursor, payload);
    k_gemm<<<NWG, 256, 0, stream>>>(x, BT, hb, U);
    k_final<<<N_NODES / 4, 256, 0, stream>>>(out, hb, U, start, payload, coeff,
                                             b_self, gamma, beta);
}

// Round 10
// 277.227 us; speedup vs baseline: 1.0791x; 1.0791x over previous
//
#include <hip/hip_runtime.h>
#include <hip/hip_bf16.h>

#define N_NODES 100000
#define D 256
#define R_REL 8
#define E_EDGES 40000
#define LN_EPS 1e-5f
#define ETOT (R_REL * E_EDGES)                    // 320000
#define SCAN_CH 1024
#define SCAN_NB ((N_NODES + SCAN_CH - 1) / SCAN_CH)  // 98
#define NROWT ((N_NODES + 127) / 128)             // 782
#define NWG (NROWT * 10)                          // 7820

typedef __attribute__((ext_vector_type(8))) short short8;
typedef __attribute__((ext_vector_type(4))) float f32x4;
typedef unsigned char uchar;

__device__ inline ushort bf16u(float f) {
    __hip_bfloat16 h = __float2bfloat16(f);
    return *reinterpret_cast<ushort*>(&h);
}
__device__ inline float bf2f(ushort u) { return __uint_as_float(((unsigned)u) << 16); }

// ---------------------------------------------------------------------------
// BT[o][d] = BigB[d][o] bf16, BigB = [w_self | bases0..3] (256 x 1280).
__global__ __launch_bounds__(256) void k_prepB(const float* __restrict__ w_self,
                                               const float* __restrict__ bases,
                                               ushort* __restrict__ BT) {
    __shared__ float tile[64][65];
    int ot = blockIdx.x >> 2, dt = blockIdx.x & 3;
    int o0 = ot * 64, d0 = dt * 64;
    int m = o0 >> 8;                       // 0 = w_self, 1..4 = bases[m-1]
    const float* src = (m == 0) ? w_self : bases + (size_t)(m - 1) * D * D;
    int ol0 = o0 & 255;
    int t = threadIdx.x;
    int cl = t & 63, rw = t >> 6;
    for (int i = 0; i < 16; ++i) {
        int dl = i * 4 + rw;
        tile[dl][cl] = src[(size_t)(d0 + dl) * D + ol0 + cl];
    }
    __syncthreads();
    for (int i = 0; i < 16; ++i) {
        int ol = i * 4 + rw;
        BT[(size_t)(o0 + ol) * D + d0 + cl] = bf16u(tile[cl][ol]);
    }
}

// x (f32) -> xb (bf16), 8 elems/thread
__global__ __launch_bounds__(256) void k_prepX(const float* __restrict__ x,
                                               ushort* __restrict__ xb) {
    size_t idx = (size_t)blockIdx.x * 256 + threadIdx.x;
    const float4* xp = (const float4*)(x + idx * 8);
    float4 f0 = xp[0], f1 = xp[1];
    short8 v;
    v[0] = (short)bf16u(f0.x); v[1] = (short)bf16u(f0.y);
    v[2] = (short)bf16u(f0.z); v[3] = (short)bf16u(f0.w);
    v[4] = (short)bf16u(f1.x); v[5] = (short)bf16u(f1.y);
    v[6] = (short)bf16u(f1.z); v[7] = (short)bf16u(f1.w);
    *(short8*)(xb + idx * 8) = v;
}

// ---------------------------------------------------------------------------
// CSR over dst (all relations together)
__global__ void k_count(const int* __restrict__ ei, int* __restrict__ cnt) {
    int idx = blockIdx.x * blockDim.x + threadIdx.x;
    if (idx >= ETOT) return;
    int r = idx / E_EDGES, e = idx % E_EDGES;
    int dst = ei[(r * 2 + 1) * E_EDGES + e];
    atomicAdd(&cnt[dst], 1);
}

__global__ __launch_bounds__(256) void k_scanA(const int* __restrict__ cnt,
                                               int* __restrict__ start,
                                               int* __restrict__ sumsA) {
    __shared__ int sc[256];
    int t = threadIdx.x;
    int base = blockIdx.x * SCAN_CH + t * 4;
    int v0 = (base + 0 < N_NODES) ? cnt[base + 0] : 0;
    int v1 = (base + 1 < N_NODES) ? cnt[base + 1] : 0;
    int v2 = (base + 2 < N_NODES) ? cnt[base + 2] : 0;
    int v3 = (base + 3 < N_NODES) ? cnt[base + 3] : 0;
    int ts = v0 + v1 + v2 + v3;
    sc[t] = ts;
    __syncthreads();
    for (int off = 1; off < 256; off <<= 1) {
        int val = (t >= off) ? sc[t - off] : 0;
        __syncthreads();
        sc[t] += val;
        __syncthreads();
    }
    int excl = sc[t] - ts;
    if (base + 0 < N_NODES) start[base + 0] = excl;
    if (base + 1 < N_NODES) start[base + 1] = excl + v0;
    if (base + 2 < N_NODES) start[base + 2] = excl + v0 + v1;
    if (base + 3 < N_NODES) start[base + 3] = excl + v0 + v1 + v2;
    if (t == 255) sumsA[blockIdx.x] = sc[255];
}

__global__ __launch_bounds__(256) void k_scanB(const int* __restrict__ sumsA,
                                               int* __restrict__ sumsB) {
    __shared__ int sc[256];
    int t = threadIdx.x;
    int i0 = t * 4;
    int v0 = (i0 + 0 < SCAN_NB) ? sumsA[i0 + 0] : 0;
    int v1 = (i0 + 1 < SCAN_NB) ? sumsA[i0 + 1] : 0;
    int v2 = (i0 + 2 < SCAN_NB) ? sumsA[i0 + 2] : 0;
    int v3 = (i0 + 3 < SCAN_NB) ? sumsA[i0 + 3] : 0;
    int ts = v0 + v1 + v2 + v3;
    sc[t] = ts;
    __syncthreads();
    for (int off = 1; off < 256; off <<= 1) {
        int val = (t >= off) ? sc[t - off] : 0;
        __syncthreads();
        sc[t] += val;
        __syncthreads();
    }
    int excl = sc[t] - ts;
    if (i0 + 0 < SCAN_NB) sumsB[i0 + 0] = excl;
    if (i0 + 1 < SCAN_NB) sumsB[i0 + 1] = excl + v0;
    if (i0 + 2 < SCAN_NB) sumsB[i0 + 2] = excl + v0 + v1;
    if (i0 + 3 < SCAN_NB) sumsB[i0 + 3] = excl + v0 + v1 + v2;
}

__global__ __launch_bounds__(256) void k_scanC(int* __restrict__ start,
                                               const int* __restrict__ sumsB,
                                               int* __restrict__ cursor) {
    int idx = blockIdx.x * blockDim.x + threadIdx.x;
    if (idx < N_NODES) {
        int v = start[idx] + sumsB[idx / SCAN_CH];
        start[idx] = v;
        cursor[idx] = v;
    }
    if (idx == 0) start[N_NODES] = ETOT;
}

// payload = (r<<20) | src, slotted per dst
__global__ void k_scatter(const int* __restrict__ ei, int* __restrict__ cursor,
                          int* __restrict__ payload) {
    int idx = blockIdx.x * blockDim.x + threadIdx.x;
    if (idx >= ETOT) return;
    int r = idx / E_EDGES, e = idx % E_EDGES;
    int src = ei[r * 2 * E_EDGES + e];
    int dst = ei[(r * 2 + 1) * E_EDGES + e];
    int pos = atomicAdd(&cursor[dst], 1);
    payload[pos] = (r << 20) | src;
}

// ---------------------------------------------------------------------------
// [hb | U] = xb @ BT^T.  128x128 tile, BK=64, ALL staging via global_load_lds
// (R8 structure). Flattened grid + m204 bijective XCD swizzle: all 10 passes
// of a row-tile run on one XCD -> A-tile HBM-fetched once, BT L2-resident.
// pass 0..1 -> hb (bf16); pass 2..9 -> U plane (fp8 e4m3, value*64).
__global__ __launch_bounds__(256, 2) void k_gemm(const ushort* __restrict__ xb,
                                                 const ushort* __restrict__ BT,
                                                 ushort* __restrict__ hb,
                                                 uchar* __restrict__ U) {
    __shared__ ushort As[2][128 * 64];     // 2 x 16 KB
    __shared__ ushort Bs[2][128 * 64];     // 2 x 16 KB
    int t = threadIdx.x;

    // m204 bijective XCD-chunked swizzle (NWG = 7820, 8 XCDs)
    const int q = NWG / 8, r8 = NWG % 8;
    int dd = blockIdx.x;
    int xcd = dd & 7, slot = dd >> 3;
    int wgid = (xcd < r8 ? xcd * (q + 1) : r8 * (q + 1) + (xcd - r8) * q) + slot;
    int rowtile = wgid / 10, pass = wgid % 10;
    int row0 = rowtile * 128;

    int l = t & 63, w = t >> 6;
    int wr = w >> 1, wc = w & 1;           // 2 x 2 wave grid
    int lr = l & 15, lg = l >> 4;

    // staging: linear LDS dest, inverse-swizzled global source (T21)
    auto stageA = [&](int buf, int kt) {
#pragma unroll
        for (int p = 0; p < 4; ++p) {
            int o = p * 4096 + t * 16;                  // linear byte in 16KB tile
            int rowA = o >> 7;                          // 128B per row (64 k bf16)
            int colb = (o & 127) ^ ((rowA & 7) << 4);
            int srcrow = min(row0 + rowA, N_NODES - 1);
            const char* gp = (const char*)xb + ((size_t)srcrow * D + kt * 64) * 2 + colb;
            char* lp = (char*)&As[buf][0] + p * 4096 + (t >> 6) * 1024;  // wave-uniform
            __builtin_amdgcn_global_load_lds(
                (const __attribute__((address_space(1))) void*)gp,
                (__attribute__((address_space(3))) void*)lp, 16, 0, 0);
        }
    };
    auto stageB = [&](int buf, int kt) {
#pragma unroll
        for (int p = 0; p < 4; ++p) {
            int o = p * 4096 + t * 16;
            int rowB = o >> 7;
            int colb = (o & 127) ^ ((rowB & 7) << 4);
            const char* gp = (const char*)BT +
                ((size_t)(pass * 128 + rowB) * D + kt * 64) * 2 + colb;
            char* lp = (char*)&Bs[buf][0] + p * 4096 + (t >> 6) * 1024;
            __builtin_amdgcn_global_load_lds(
                (const __attribute__((address_space(1))) void*)gp,
                (__attribute__((address_space(3))) void*)lp, 16, 0, 0);
        }
    };

    f32x4 acc[4][4] = {};
    stageA(0, 0); stageB(0, 0);
    int buf = 0;
    for (int kt = 0; kt < 4; ++kt) {
        __syncthreads();                   // buf ready; prior reads of buf^1 done
        if (kt < 3) { stageA(buf ^ 1, kt + 1); stageB(buf ^ 1, kt + 1); }
#pragma unroll
        for (int kk = 0; kk < 2; ++kk) {
            int kb = kk * 64 + lg * 16;    // byte col within 128B row
            short8 a[4], b[4];
#pragma unroll
            for (int mi = 0; mi < 4; ++mi) {
                int row = wr * 64 + mi * 16 + lr;
                a[mi] = *(const short8*)((const char*)&As[buf][0] +
                         row * 128 + (kb ^ ((row & 7) << 4)));
            }
#pragma unroll
            for (int ni = 0; ni < 4; ++ni) {
                int rb = wc * 64 + ni * 16 + lr;
                b[ni] = *(const short8*)((const char*)&Bs[buf][0] +
                         rb * 128 + (kb ^ ((rb & 7) << 4)));
            }
#pragma unroll
            for (int mi = 0; mi < 4; ++mi)
#pragma unroll
                for (int ni = 0; ni < 4; ++ni)
                    acc[mi][ni] = __builtin_amdgcn_mfma_f32_16x16x32_bf16(
                        a[mi], b[ni], acc[mi][ni], 0, 0, 0);
        }
        buf ^= 1;
    }

    // ---- epilogue (regs only)
    if (pass < 2) {
        int colbase = pass * 128 + wc * 64 + lr;
#pragma unroll
        for (int mi = 0; mi < 4; ++mi)
#pragma unroll
            for (int j = 0; j < 4; ++j) {
                int row = row0 + wr * 64 + mi * 16 + lg * 4 + j;
                if (row < N_NODES) {
                    ushort* op = hb + (size_t)row * D + colbase;
#pragma unroll
                    for (int ni = 0; ni < 4; ++ni) op[ni * 16] = bf16u(acc[mi][ni][j]);
                }
            }
    } else {
        int pl = pass - 2;
        int plane = pl >> 1;
        int colbase = (pl & 1) * 128 + wc * 64 + lr;
#pragma unroll
        for (int mi = 0; mi < 4; ++mi)
#pragma unroll
            for (int j = 0; j < 4; ++j) {
                int row = row0 + wr * 64 + mi * 16 + lg * 4 + j;
                if (row < N_NODES) {
                    // U layout: [src][plane*256 + col], fp8 e4m3 of value*64
                    uchar* up = U + (size_t)row * 1024 + plane * 256 + colbase;
                    unsigned p01 = __builtin_amdgcn_cvt_pk_fp8_f32(
                        acc[mi][0][j] * 64.0f, acc[mi][1][j] * 64.0f, 0, 0);
                    unsigned p23 = __builtin_amdgcn_cvt_pk_fp8_f32(
                        acc[mi][2][j] * 64.0f, acc[mi][3][j] * 64.0f, 0, 0);
                    up[0]  = (uchar)(p01 & 0xFF);
                    up[16] = (uchar)((p01 >> 8) & 0xFF);
                    up[32] = (uchar)(p23 & 0xFF);
                    up[48] = (uchar)((p23 >> 8) & 0xFF);
                }
            }
    }
}

// ---------------------------------------------------------------------------
// Per dst node (one wave each). Lane owns output cols lane*4..lane*4+3.
// Per edge: one dword per plane (4 coalesced 256B wave-loads); accumulate in
// regs; no cross-lane work until the LN reduce.
__global__ __launch_bounds__(256) void k_final(float* __restrict__ out,
                                               const ushort* __restrict__ hb,
                                               const uchar* __restrict__ U,
                                               const int* __restrict__ start,
                                               const int* __restrict__ payload,
                                               const float* __restrict__ coeff,
                                               const float* __restrict__ bias,
                                               const float* __restrict__ gamma,
                                               const float* __restrict__ beta) {
    __shared__ float cf[32];
    int t = threadIdx.x;
    if (t < 32) cf[t] = coeff[t];
    __syncthreads();
    int lane = t & 63, w = t >> 6;
    int n = blockIdx.x * 4 + w;
    int s = start[n], e = start[n + 1];

    // per-relation degree counts packed 8x8 bits
    unsigned long long cnt64 = 0;
    for (int p = s; p < e; ++p)
        cnt64 += 1ull << ((payload[p] >> 20) * 8);

    float msg[4] = {0.f, 0.f, 0.f, 0.f};
    for (int p = s; p < e; ++p) {
        int pk = payload[p];
        int r = pk >> 20, src = pk & 0xFFFFF;
        float dg = (float)((unsigned)(cnt64 >> (r * 8)) & 255u);
        float inv = __builtin_amdgcn_rcpf(dg) * 0.015625f;
        float4 wv = *(const float4*)&cf[r * 4];
        const uchar* up = U + (size_t)src * 1024 + lane * 4;
        unsigned v0 = *(const unsigned*)(up);
        unsigned v1 = *(const unsigned*)(up + 256);
        unsigned v2 = *(const unsigned*)(up + 512);
        unsigned v3 = *(const unsigned*)(up + 768);
        float w0 = wv.x * inv, w1 = wv.y * inv, w2 = wv.z * inv, w3 = wv.w * inv;
        msg[0] += w0 * __builtin_amdgcn_cvt_f32_fp8(v0, 0)
                + w1 * __builtin_amdgcn_cvt_f32_fp8(v1, 0)
                + w2 * __builtin_amdgcn_cvt_f32_fp8(v2, 0)
                + w3 * __builtin_amdgcn_cvt_f32_fp8(v3, 0);
        msg[1] += w0 * __builtin_amdgcn_cvt_f32_fp8(v0, 1)
                + w1 * __builtin_amdgcn_cvt_f32_fp8(v1, 1)
                + w2 * __builtin_amdgcn_cvt_f32_fp8(v2, 1)
                + w3 * __builtin_amdgcn_cvt_f32_fp8(v3, 1);
        msg[2] += w0 * __builtin_amdgcn_cvt_f32_fp8(v0, 2)
                + w1 * __builtin_amdgcn_cvt_f32_fp8(v1, 2)
                + w2 * __builtin_amdgcn_cvt_f32_fp8(v2, 2)
                + w3 * __builtin_amdgcn_cvt_f32_fp8(v3, 2);
        msg[3] += w0 * __builtin_amdgcn_cvt_f32_fp8(v0, 3)
                + w1 * __builtin_amdgcn_cvt_f32_fp8(v1, 3)
                + w2 * __builtin_amdgcn_cvt_f32_fp8(v2, 3)
                + w3 * __builtin_amdgcn_cvt_f32_fp8(v3, 3);
    }

    int col = lane * 4;
    size_t ro = (size_t)n * D + col;
    ushort4 hu = *(const ushort4*)&hb[ro];
    float4 bv = *(const float4*)&bias[col];
    float a[4];
    a[0] = bf2f(hu.x) + bv.x + msg[0];
    a[1] = bf2f(hu.y) + bv.y + msg[1];
    a[2] = bf2f(hu.z) + bv.z + msg[2];
    a[3] = bf2f(hu.w) + bv.w + msg[3];
    float sum = 0.f, sq = 0.f;
#pragma unroll
    for (int j = 0; j < 4; ++j) {
        a[j] = a[j] / (1.f + expf(-a[j]));
        sum += a[j]; sq += a[j] * a[j];
    }
#pragma unroll
    for (int off = 32; off >= 1; off >>= 1) {
        sum += __shfl_xor(sum, off, 64);
        sq  += __shfl_xor(sq,  off, 64);
    }
    float mean = sum * (1.0f / 256.0f);
    float var = sq * (1.0f / 256.0f) - mean * mean;
    float rs = rsqrtf(var + LN_EPS);
    float4 g4 = *(const float4*)&gamma[col];
    float4 b4 = *(const float4*)&beta[col];
    float4 o4;
    o4.x = (a[0] - mean) * rs * g4.x + b4.x;
    o4.y = (a[1] - mean) * rs * g4.y + b4.y;
    o4.z = (a[2] - mean) * rs * g4.z + b4.z;
    o4.w = (a[3] - mean) * rs * g4.w + b4.w;
    *(float4*)&out[ro] = o4;
}

// ---------------------------------------------------------------------------
extern "C" void kernel_launch(void* const* d_in, const int* in_sizes, int n_in,
                              void* d_out, int out_size, void* d_ws, size_t ws_size,
                              hipStream_t stream) {
    const float* x      = (const float*)d_in[0];
    const int*   ei     = (const int*)d_in[1];
    const float* bases  = (const float*)d_in[2];
    const float* coeff  = (const float*)d_in[3];
    const float* w_self = (const float*)d_in[4];
    const float* b_self = (const float*)d_in[5];
    const float* gamma  = (const float*)d_in[6];
    const float* beta   = (const float*)d_in[7];
    float* out = (float*)d_out;

    ushort* BT  = (ushort*)d_ws;                          // 1280*256 bf16 (0.66 MB)
    ushort* xb  = BT + (size_t)1280 * D;                  // N*256 bf16 (51.2 MB)
    ushort* hb  = xb + (size_t)N_NODES * D;               // N*256 bf16 (51.2 MB)
    uchar*  U   = (uchar*)(hb + (size_t)N_NODES * D);     // N*1024 fp8 (102.4 MB)
    int* cnt    = (int*)(U + (size_t)N_NODES * 1024);     // N
    int* start  = cnt + N_NODES;                          // N+1
    int* cursor = start + N_NODES + 1;                    // N
    int* sumsA  = cursor + N_NODES;                       // 98 (pad 128)
    int* sumsB  = sumsA + 128;                            // 98 (pad 128)
    int* payload = sumsB + 128;                           // ETOT

    hipMemsetAsync(cnt, 0, (size_t)N_NODES * sizeof(int), stream);

    k_prepB<<<80, 256, 0, stream>>>(w_self, bases, BT);
    k_prepX<<<(N_NODES * D / 8 + 255) / 256, 256, 0, stream>>>(x, xb);
    k_count<<<(ETOT + 255) / 256, 256, 0, stream>>>(ei, cnt);
    k_scanA<<<SCAN_NB, 256, 0, stream>>>(cnt, start, sumsA);
    k_scanB<<<1, 256, 0, stream>>>(sumsA, sumsB);
    k_scanC<<<(N_NODES + 255) / 256, 256, 0, stream>>>(start, sumsB, cursor);
    k_scatter<<<(ETOT + 255) / 256, 256, 0, stream>>>(ei, cursor, payload);
    k_gemm<<<NWG, 256, 0, stream>>>(xb, BT, hb, U);
    k_final<<<N_NODES / 4, 256, 0, stream>>>(out, hb, U, start, payload, coeff,
                                             b_self, gamma, beta);
}